// Round 15
// baseline (95.115 us; speedup 1.0000x reference)
//
#include <hip/hip_runtime.h>

// Problem: H=W=384, F=K=256. M = 147456 rows.
// out[m,f] = sum_k d[m,k] * y[k,f],  y = x[stations] @ W  (256x256, tiny)
#define FF 256
#define KK 256
#define RR 16                  // rows per stripe
#define STRIPES 8              // stripes per block -> 128 rows/block
#define NBLK 4608              // 1152 rowgroups * 4 col-quarters
#define QC 64                  // cols per block (quarter of FF)

typedef __attribute__((ext_vector_type(8))) short bf16x8;   // 8 bf16 (4 VGPR)
typedef __attribute__((ext_vector_type(4))) float f32x4;    // MFMA C/D frag
typedef __attribute__((ext_vector_type(4))) short short4v;  // 4 bf16 (8 B)

// float -> bf16 bits, round-to-nearest-even
__device__ inline short f2bf(float x) {
    unsigned u = __float_as_uint(x);
    unsigned r = u + 0x7FFFu + ((u >> 16) & 1u);
    return (short)(r >> 16);
}

// Kernel 1: y[k][f] = sum_j x[sx[k],sy[k],j] * W[j][f], stored bf16 in
// FRAGMENT ORDER so kernel-2 B loads are lane-contiguous 16B/lane:
//   idx(k,f) = ((f>>4)*8 + (k>>5))*512 + (((k>>3)&3)*16 + (f&15))*8 + (k&7)
__global__ __launch_bounds__(256) void station_kernel(
        const float* __restrict__ x, const float* __restrict__ W,
        const int* __restrict__ sx, const int* __restrict__ sy,
        short* __restrict__ yp) {
    __shared__ float xrow[FF];
    const int k = blockIdx.x;
    const int f = threadIdx.x;
    const long base = ((long)sx[k] * 384 + (long)sy[k]) * FF;
    xrow[f] = x[base + f];
    __syncthreads();
    float acc = 0.f;
    #pragma unroll 8
    for (int j = 0; j < FF; ++j)
        acc += xrow[j] * W[j * FF + f];   // coalesced across f
    const int idx = ((f >> 4) * 8 + (k >> 5)) * 512
                  + (((k >> 3) & 3) * 16 + (f & 15)) * 8 + (k & 7);
    yp[idx] = f2bf(acc);
}

// Kernel 2: R13 cadence, but wave owns only 16 cols (bfrag[8][1] = 32 AGPR)
// so ~90 regs/wave -> 5 resident blocks/CU = 5 independent barrier groups
// overlapping each other's per-stripe fixed latencies. Block = 128 rows x
// 64-col quarter, 8 stripes; C via LDS-linearized stores (proven R13 win).
__global__ __launch_bounds__(256, 5) void gemm_kernel(
        const float* __restrict__ d, const short* __restrict__ yp,
        float* __restrict__ out) {
    __shared__ __align__(16) short ldsA[2][RR * KK];   // 2 x 8 KB A, swizzled
    __shared__ __align__(16) float ldsC[RR * QC];      // 4 KB C staging
    const int t    = threadIdx.x;
    const int lane = t & 63;
    const int wid  = t >> 6;          // 0..3: 16-col slice within quarter
    const int l15  = lane & 15;
    const int lg   = lane >> 4;       // 0..3: k-subgroup

    // Bijective XCD swizzle (NBLK % 8 == 0): the 4 quarters sharing a
    // rowgroup get consecutive work ids -> same XCD -> d fetched once.
    const int work    = (blockIdx.x & 7) * (NBLK / 8) + (blockIdx.x >> 3);
    const int quarter = work & 3;               // 64-col quarter
    const long mblk   = (long)(work >> 2) * (RR * STRIPES);

    char* lb0 = (char*)ldsA[0];
    char* lb1 = (char*)ldsA[1];

    // ---- B fragments: 8 x 16B/lane coalesced loads, once per block ----
    bf16x8 bfrag[8];
    const int g = quarter * 4 + wid;            // 16-col group 0..15
    #pragma unroll
    for (int kf = 0; kf < 8; ++kf)
        bfrag[kf] = *(const bf16x8*)(yp + ((g * 8 + kf) << 9) + (lane << 3));
    asm volatile("" :
        "+v"(bfrag[0]), "+v"(bfrag[1]), "+v"(bfrag[2]), "+v"(bfrag[3]),
        "+v"(bfrag[4]), "+v"(bfrag[5]), "+v"(bfrag[6]), "+v"(bfrag[7]));

    // staging geometry: pass p covers rows p*4 + (t>>6), lane writes 8B at
    // col-byte 8*(t&63). 4 passes x 256 thr x 4 floats = 4096 = 16 rows.
    const int srow0 = t >> 6;
    const int scol  = (t & 63) * 8;

    // ---- prologue: load + stage stripe 0 into buf0 ----
    float4 pv[4];
    {
        const float* dp = d + mblk * KK;
        #pragma unroll
        for (int p = 0; p < 4; ++p)
            pv[p] = *(const float4*)(dp + (p * 256 + t) * 4);
        #pragma unroll
        for (int p = 0; p < 4; ++p) {
            const int row = p * 4 + srow0;
            int byte = row * 512 + scol;
            byte ^= (row & 7) << 4;               // bank swizzle (G4)
            short4v b;
            b.x = f2bf(pv[p].x); b.y = f2bf(pv[p].y);
            b.z = f2bf(pv[p].z); b.w = f2bf(pv[p].w);
            *(short4v*)(lb0 + byte) = b;
        }
    }
    __syncthreads();

    for (int s = 0; s < STRIPES; ++s) {
        const long m0 = mblk + (long)s * RR;
        char* cur = (s & 1) ? lb1 : lb0;
        char* nxt = (s & 1) ? lb0 : lb1;

        // (1) issue next stripe's global loads — vmcnt waits land at stage
        if (s + 1 < STRIPES) {
            const float* dp = d + (m0 + RR) * KK;
            #pragma unroll
            for (int p = 0; p < 4; ++p)
                pv[p] = *(const float4*)(dp + (p * 256 + t) * 4);
        }

        // (2) compute current stripe: A from LDS, B resident (8 MFMA/wave)
        f32x4 acc;
        #pragma unroll
        for (int q = 0; q < 4; ++q) acc[q] = 0.f;

        #pragma unroll
        for (int kf = 0; kf < 8; ++kf) {
            const int cb = kf * 64 + lg * 16;
            const int xo = (l15 & 7) << 4;
            bf16x8 a0 = *(const bf16x8*)(cur + ((l15 * 512 + cb) ^ xo));
            acc = __builtin_amdgcn_mfma_f32_16x16x32_bf16(
                      a0, bfrag[kf], acc, 0, 0, 0);
        }

        // (3) C fragments -> LDS tile (scatter), then barrier
        #pragma unroll
        for (int q = 0; q < 4; ++q)
            ldsC[(lg * 4 + q) * QC + wid * 16 + l15] = acc[q];
        __syncthreads();

        // (4) stream C tile out LINEARLY: 1024 floats in one pass;
        // per wave-instruction: 4 rows x 256 B contiguous chunks.
        {
            const int e = t * 4;                     // element index in tile
            const float4 v = *(const float4*)(ldsC + e);
            *(float4*)(out + (m0 + (e >> 6)) * FF + quarter * QC + (e & 63)) = v;
        }

        // (5) convert + LDS-write pending A stripe into nxt
        if (s + 1 < STRIPES) {
            #pragma unroll
            for (int p = 0; p < 4; ++p) {
                const int row = p * 4 + srow0;
                int byte = row * 512 + scol;
                byte ^= (row & 7) << 4;
                short4v b;
                b.x = f2bf(pv[p].x); b.y = f2bf(pv[p].y);
                b.z = f2bf(pv[p].z); b.w = f2bf(pv[p].w);
                *(short4v*)(nxt + byte) = b;
            }
        }

        // (6) close the stripe
        __syncthreads();
    }
}

extern "C" void kernel_launch(void* const* d_in, const int* in_sizes, int n_in,
                              void* d_out, int out_size, void* d_ws, size_t ws_size,
                              hipStream_t stream) {
    const float* x  = (const float*)d_in[0];
    const float* d  = (const float*)d_in[1];
    const float* W  = (const float*)d_in[2];
    const int*   sx = (const int*)d_in[3];
    const int*   sy = (const int*)d_in[4];
    float* out = (float*)d_out;
    short* yp  = (short*)d_ws;   // 256*256 bf16 = 128 KB packed fragment buffer

    station_kernel<<<dim3(KK), dim3(FF), 0, stream>>>(x, W, sx, sy, yp);
    gemm_kernel<<<dim3(NBLK), dim3(256), 0, stream>>>(d, yp, out);
}

// Round 16
// 78.041 us; speedup vs baseline: 1.2188x; 1.2188x over previous
//
#include <hip/hip_runtime.h>

// Problem: H=W=384, F=K=256. M = 147456 rows.
// out[m,f] = sum_k d[m,k] * y[k,f],  y = x[stations] @ W  (256x256, tiny)
#define FF 256
#define KK 256
#define RR 16                  // rows per stripe
#define STRIPES 4              // stripes per block -> 64 rows/block
#define NBLK 4608              // (147456/64 rowgroups) * 2 col-halves
#define HALFC 128              // cols per block (half of FF)

typedef __attribute__((ext_vector_type(8))) short bf16x8;   // 8 bf16 (4 VGPR)
typedef __attribute__((ext_vector_type(4))) float f32x4;    // MFMA C/D frag

// float -> bf16 bits, round-to-nearest-even (station kernel only)
__device__ inline short f2bf(float x) {
    unsigned u = __float_as_uint(x);
    unsigned r = u + 0x7FFFu + ((u >> 16) & 1u);
    return (short)(r >> 16);
}

__device__ inline unsigned cvtpk(float a, float b) {
    unsigned r;
    asm("v_cvt_pk_bf16_f32 %0, %1, %2" : "=v"(r) : "v"(a), "v"(b));
    return r;
}

__device__ inline bf16x8 pack8(float4 lo, float4 hi) {
    union { unsigned u[4]; bf16x8 v; } c;
    c.u[0] = cvtpk(lo.x, lo.y); c.u[1] = cvtpk(lo.z, lo.w);
    c.u[2] = cvtpk(hi.x, hi.y); c.u[3] = cvtpk(hi.z, hi.w);
    return c.v;
}

// Kernel 1: y[k][f] = sum_j x[sx[k],sy[k],j] * W[j][f], stored bf16 in
// FRAGMENT ORDER so kernel-2 B loads are lane-contiguous 16B/lane:
//   idx(k,f) = ((f>>4)*8 + (k>>5))*512 + (((k>>3)&3)*16 + (f&15))*8 + (k&7)
__global__ __launch_bounds__(256) void station_kernel(
        const float* __restrict__ x, const float* __restrict__ W,
        const int* __restrict__ sx, const int* __restrict__ sy,
        short* __restrict__ yp) {
    __shared__ float xrow[FF];
    const int k = blockIdx.x;
    const int f = threadIdx.x;
    const long base = ((long)sx[k] * 384 + (long)sy[k]) * FF;
    xrow[f] = x[base + f];
    __syncthreads();
    float acc = 0.f;
    #pragma unroll 8
    for (int j = 0; j < FF; ++j)
        acc += xrow[j] * W[j * FF + f];   // coalesced across f
    const int idx = ((f >> 4) * 8 + (k >> 5)) * 512
                  + (((k >> 3) & 3) * 16 + (f & 15)) * 8 + (k & 7);
    yp[idx] = f2bf(acc);
}

// DMA one 16-row f32 stripe via global_load_lds. LDS dest linear
// (wave-uniform base + lane*16); global SOURCE lane-permuted on 16B segs
// (seg ^= row&7) so reads apply the same XOR -> conflict-free (rule #21).
__device__ inline void dma_stripe(const float* drow0, float* buf,
                                  int wid, int lane) {
    #pragma unroll
    for (int p = 0; p < 4; ++p) {
        const int r = p * 4 + wid;                   // this wave's row
        const float* g = drow0 + (long)r * KK + ((lane ^ (r & 7)) << 2);
        float* l = buf + r * KK;                     // wave-uniform base
        __builtin_amdgcn_global_load_lds(
            (const __attribute__((address_space(1))) float*)g,
            (__attribute__((address_space(3))) float*)l, 16, 0, 0);
    }
}

// Kernel 2: R13 geometry; A via DMA (f32) with counted vmcnt + collective
// barrier (loads leave the critical path); cvt_pk in compute; C via
// scatter->LDS->linear stores (R13's proven win). Stores never drained.
__global__ __launch_bounds__(256, 4) void gemm_kernel(
        const float* __restrict__ d, const short* __restrict__ yp,
        float* __restrict__ out) {
    __shared__ __align__(16) float bufA[2][RR * KK];    // 2 x 16 KB A (f32)
    __shared__ __align__(16) float ldsC[2][RR * HALFC]; // 2 x 8 KB C staging
    const int t    = threadIdx.x;
    const int lane = t & 63;
    const int wid  = t >> 6;          // 0..3: 32-col slice within the half
    const int l15  = lane & 15;
    const int lg   = lane >> 4;       // 0..3: k-subgroup

    // Bijective XCD swizzle (NBLK % 8 == 0): row-sharing col-half pairs co-XCD.
    const int work = (blockIdx.x & 7) * (NBLK / 8) + (blockIdx.x >> 3);
    const int half = work & 1;                  // col half: 0..1 (128 cols)
    const long mblk = (long)(work >> 1) * (RR * STRIPES);

    // ---- B fragments: 16 x 16B/lane coalesced loads, once per block ----
    bf16x8 bfrag[8][2];
    #pragma unroll
    for (int kf = 0; kf < 8; ++kf)
        #pragma unroll
        for (int nf = 0; nf < 2; ++nf) {
            const int g = half * 8 + wid * 2 + nf;   // 16-col group 0..15
            bfrag[kf][nf] = *(const bf16x8*)(yp + ((g * 8 + kf) << 9) + (lane << 3));
        }
    // Anti-remat value barrier: keep them register/AGPR-resident.
    asm volatile("" :
        "+v"(bfrag[0][0]), "+v"(bfrag[0][1]), "+v"(bfrag[1][0]), "+v"(bfrag[1][1]),
        "+v"(bfrag[2][0]), "+v"(bfrag[2][1]), "+v"(bfrag[3][0]), "+v"(bfrag[3][1]),
        "+v"(bfrag[4][0]), "+v"(bfrag[4][1]), "+v"(bfrag[5][0]), "+v"(bfrag[5][1]),
        "+v"(bfrag[6][0]), "+v"(bfrag[6][1]), "+v"(bfrag[7][0]), "+v"(bfrag[7][1]));

    // ---- prologue: DMA stripe 0 (no wait here) ----
    dma_stripe(d + mblk * KK, bufA[0], wid, lane);
    __builtin_amdgcn_sched_barrier(0);

    const int s7 = l15 & 7;           // read-side XOR (matches source perm)

    #pragma unroll
    for (int s = 0; s < STRIPES; ++s) {
        const long m0 = mblk + (long)s * RR;
        const float* cur = bufA[s & 1];
        float* cst = ldsC[s & 1];

        // (A) issue next stripe's DMA (overwrite-safe: all waves passed the
        // data-publish barrier of stripe s-1 after their compute(s-1))
        if (s + 1 < STRIPES) {
            dma_stripe(d + (m0 + RR) * KK, bufA[(s + 1) & 1], wid, lane);
            __builtin_amdgcn_sched_barrier(0);
        }

        // (B) counted wait: own DMA(s) retired; C-stores stay in flight.
        //     outstanding = [DMA(s)x4][store(s-1)x2][DMA(s+1)x4] -> 6
        if (s == 0)                asm volatile("s_waitcnt vmcnt(4)" ::: "memory");
        else if (s == STRIPES - 1) asm volatile("s_waitcnt vmcnt(2)" ::: "memory");
        else                       asm volatile("s_waitcnt vmcnt(6)" ::: "memory");
        __builtin_amdgcn_sched_barrier(0);
        // (C) collective publish: after this, ALL waves' DMA(s) are in LDS
        __builtin_amdgcn_s_barrier();

        // (D) compute stripe s: ds_read f32 (XOR'd segs), cvt_pk, MFMA
        f32x4 acc[2];
        #pragma unroll
        for (int nf = 0; nf < 2; ++nf)
            #pragma unroll
            for (int q = 0; q < 4; ++q) acc[nf][q] = 0.f;

        #pragma unroll
        for (int kf = 0; kf < 8; ++kf) {
            const int seg0 = kf * 8 + lg * 2;     // 16B-seg index in row
            const float4 lo = *(const float4*)(cur + l15 * KK + (((seg0    ) ^ s7) << 2));
            const float4 hi = *(const float4*)(cur + l15 * KK + (((seg0 + 1) ^ s7) << 2));
            const bf16x8 a = pack8(lo, hi);
            #pragma unroll
            for (int nf = 0; nf < 2; ++nf)
                acc[nf] = __builtin_amdgcn_mfma_f32_16x16x32_bf16(
                              a, bfrag[kf][nf], acc[nf], 0, 0, 0);
        }

        // (E) scatter C -> LDS tile
        #pragma unroll
        for (int nf = 0; nf < 2; ++nf)
            #pragma unroll
            for (int q = 0; q < 4; ++q)
                cst[(lg * 4 + q) * HALFC + wid * 32 + nf * 16 + l15]
                    = acc[nf][q];

        // (F) lgkm-only publish of the scatter (no vmcnt drain)
        asm volatile("s_waitcnt lgkmcnt(0)" ::: "memory");
        __builtin_amdgcn_s_barrier();
        __builtin_amdgcn_sched_barrier(0);

        // (G) stream C tile out LINEARLY (fire-and-forget): per wave-instr
        //     2 rows x 512 B contiguous (4 full cache lines).
        #pragma unroll
        for (int p = 0; p < 2; ++p) {
            const int e = p * 1024 + t * 4;          // element index in tile
            const float4 v = *(const float4*)(cst + e);
            *(float4*)(out + (m0 + (e >> 7)) * FF + half * HALFC + (e & 127)) = v;
        }
    }
}

extern "C" void kernel_launch(void* const* d_in, const int* in_sizes, int n_in,
                              void* d_out, int out_size, void* d_ws, size_t ws_size,
                              hipStream_t stream) {
    const float* x  = (const float*)d_in[0];
    const float* d  = (const float*)d_in[1];
    const float* W  = (const float*)d_in[2];
    const int*   sx = (const int*)d_in[3];
    const int*   sy = (const int*)d_in[4];
    float* out = (float*)d_out;
    short* yp  = (short*)d_ws;   // 256*256 bf16 = 128 KB packed fragment buffer

    station_kernel<<<dim3(KK), dim3(FF), 0, stream>>>(x, W, sx, sy, yp);
    gemm_kernel<<<dim3(NBLK), dim3(256), 0, stream>>>(d, yp, out);
}